// Round 5
// baseline (217.920 us; speedup 1.0000x reference)
//
#include <hip/hip_runtime.h>
#include <hip/hip_bf16.h>

#define H 1024
#define BATCH 16384

typedef unsigned short u16;
typedef u16 u16x8 __attribute__((ext_vector_type(8)));
typedef __bf16 bf16x8 __attribute__((ext_vector_type(8)));
typedef float f32x4 __attribute__((ext_vector_type(4)));

typedef __attribute__((address_space(3))) unsigned int lds_uint;
typedef __attribute__((address_space(1))) const unsigned int glob_uint;

__device__ __forceinline__ u16 f2bf(float f) {
  unsigned int u = __float_as_uint(f);
  u += 0x7fffu + ((u >> 16) & 1u);   // round-to-nearest-even
  return (u16)(u >> 16);
}

// ================= FAST PATH =================
// ws float offsets
#define WS_XSUMP   0                      // [256][1024] per-block col-sum partials
#define WS_XSUM    (WS_XSUMP + 256 * H)   // [1024] reduced col sums
#define WS_ORAWP   (WS_XSUM + H)          // [16][1024] vecmat partials (pre-scaled 1/B)
#define WS_POSVP   (WS_ORAWP + 16 * H)    // [5][1024]
#define WS_NEGHP   (WS_POSVP + 5 * H)     // [5][1024]
#define WS_SCRATCH (WS_NEGHP + 5 * H)     // unused spare
#define WS_BF16    (WS_SCRATCH + 16)      // Xb then Wbt (u16), 16B-aligned

// ---- K1: prep, 1024 threads/block:
//   blocks 0..255   convx: 64 rows each, 4 row-groups of 16, LDS-reduced col partials
//   blocks 256..319 convw: 4 transposed 64x64 tiles each
//   blocks 320..324 stdp partials: one 20-step t-segment each
__global__ __launch_bounds__(1024) void prep_kernel(const float* __restrict__ X,
                                                    const float* __restrict__ W,
                                                    u16* __restrict__ Xb,
                                                    u16* __restrict__ Wbt,
                                                    float* __restrict__ ws,
                                                    const float* __restrict__ pre,
                                                    const float* __restrict__ post,
                                                    const float* __restrict__ win,
                                                    const float* __restrict__ dec) {
  __shared__ __align__(16) unsigned char smem[4 * 64 * 72 * 2];  // 36864 B
  const int b = blockIdx.x, tid = threadIdx.x;
  if (b < 256) {
    // --- convert X fp32->bf16, column partial sums (no atomics) ---
    float* red = (float*)smem;                 // [4][1024]
    const int g = tid >> 8, c = tid & 255;
    const size_t r0 = (size_t)b * 64 + g * 16;
    float s0 = 0.f, s1 = 0.f, s2 = 0.f, s3 = 0.f;
#pragma unroll 4
    for (int r = 0; r < 16; ++r) {
      size_t off = (r0 + r) * H + c * 4;
      const float4 v = *(const float4*)&X[off];
      ushort4 h;
      h.x = f2bf(v.x); h.y = f2bf(v.y); h.z = f2bf(v.z); h.w = f2bf(v.w);
      *(ushort4*)&Xb[off] = h;
      s0 += v.x; s1 += v.y; s2 += v.z; s3 += v.w;
    }
    red[g * 1024 + c * 4 + 0] = s0;
    red[g * 1024 + c * 4 + 1] = s1;
    red[g * 1024 + c * 4 + 2] = s2;
    red[g * 1024 + c * 4 + 3] = s3;
    __syncthreads();
    if (g == 0) {
#pragma unroll
      for (int j = 0; j < 4; ++j) {
        int cc = c * 4 + j;
        ws[WS_XSUMP + b * H + cc] =
            red[cc] + red[1024 + cc] + red[2048 + cc] + red[3072 + cc];
      }
    }
  } else if (b < 320) {
    // --- convert + transpose W -> Wbt bf16 [n][k], 4 tiles per block ---
    u16* t = (u16*)smem;                       // [4][64][72]
    const int b2 = b - 256;
    const int g = tid >> 8, sub = tid & 255;
    const int k0 = (b2 & 15) * 64;
    const int n0 = ((b2 >> 4) * 4 + g) * 64;
    u16* tg = t + g * 64 * 72;
    const int rb = sub >> 4, c4 = sub & 15;
#pragma unroll
    for (int i = 0; i < 4; ++i) {
      int r = rb + i * 16;
      const float4 v = *(const float4*)&W[(size_t)(k0 + r) * H + n0 + c4 * 4];
      tg[(c4 * 4 + 0) * 72 + r] = f2bf(v.x);
      tg[(c4 * 4 + 1) * 72 + r] = f2bf(v.y);
      tg[(c4 * 4 + 2) * 72 + r] = f2bf(v.z);
      tg[(c4 * 4 + 3) * 72 + r] = f2bf(v.w);
    }
    __syncthreads();
    const int seg = sub & 7;
#pragma unroll
    for (int p = 0; p < 2; ++p) {
      int wr = p * 32 + (sub >> 3);
      *(u16x8*)&Wbt[(size_t)(n0 + wr) * H + k0 + seg * 8] = *(const u16x8*)&tg[wr * 72 + seg * 8];
    }
  } else {
    // --- STDP weighted history partials ---
    const int seg = b - 320;                   // 0..4
    const int col = tid;                       // 0..1023
    const int t0 = 1 + seg * 20;
    int tend = t0 + 20; if (tend > 100) tend = 100;
    float wd = win[0] * dec[0];
    float ps = 0.f, ns = 0.f;
    for (int tt = t0; tt < tend; ++tt) {
      float w = 0.01f * expf(-(float)(101 - tt) * wd);
      ps += w * pre[tt * H + col];
      if (tt >= 2) ns += w * post[tt * H + col];
    }
    ws[WS_POSVP + seg * H + col] = ps;
    ws[WS_NEGHP + seg * H + col] = ns;
  }
}

// ---- K2: 1024 GEMM blocks (exactly 4 rounds on 256 CUs); blocks 0..63 append
// the cheap vecmat after their tile epilogue.
// GEMM: 128x128 tile, BK=32, 16 KB LDS, global_load_lds w=16
__global__ __launch_bounds__(256) void gemm_vm_kernel(const u16* __restrict__ Xb,
                                                      const u16* __restrict__ Wbt,
                                                      const float* __restrict__ meta,
                                                      const float* __restrict__ W,
                                                      float* __restrict__ ws,
                                                      float* __restrict__ out) {
  __shared__ __align__(16) u16 lA[128 * 32];  // 8 KB: [m][k]
  __shared__ __align__(16) u16 lB[128 * 32];  // 8 KB: [n][k]
  __shared__ float xs[64];

  const int b = blockIdx.x, tid = threadIdx.x;
  const int mt = b & 127, nt = b >> 7;
  const size_t row0 = (size_t)mt * 128;
  const int col0 = nt * 128;
  const int wave = tid >> 6;
  const int lane = tid & 63;
  const int quad = lane >> 4;
  const int l16 = lane & 15;
  const int wm = wave >> 1, wn = wave & 1;

  const int sr = lane >> 2;
  const int sk = (lane & 3) * 8;

  f32x4 acc[4][4];
#pragma unroll
  for (int i = 0; i < 4; ++i)
#pragma unroll
    for (int j = 0; j < 4; ++j) acc[i][j] = (f32x4){0.f, 0.f, 0.f, 0.f};

  for (int k0 = 0; k0 < H; k0 += 32) {
#pragma unroll
    for (int i = 0; i < 2; ++i) {
      const int rg = i * 64 + wave * 16;  // wave-uniform row group
      const u16* ga = &Xb[(row0 + rg + sr) * H + k0 + sk];
      const u16* gb = &Wbt[(size_t)(col0 + rg + sr) * H + k0 + sk];
      __builtin_amdgcn_global_load_lds((glob_uint*)ga, (lds_uint*)&lA[rg * 32], 16, 0, 0);
      __builtin_amdgcn_global_load_lds((glob_uint*)gb, (lds_uint*)&lB[rg * 32], 16, 0, 0);
    }
    __syncthreads();

    bf16x8 av[4], bv[4];
#pragma unroll
    for (int f = 0; f < 4; ++f) {
      av[f] = __builtin_bit_cast(bf16x8, *(const u16x8*)&lA[(wm * 64 + f * 16 + l16) * 32 + quad * 8]);
      bv[f] = __builtin_bit_cast(bf16x8, *(const u16x8*)&lB[(wn * 64 + f * 16 + l16) * 32 + quad * 8]);
    }
#pragma unroll
    for (int fm = 0; fm < 4; ++fm)
#pragma unroll
      for (int fn = 0; fn < 4; ++fn)
        acc[fm][fn] = __builtin_amdgcn_mfma_f32_16x16x32_bf16(av[fm], bv[fn], acc[fm][fn], 0, 0, 0);
    __syncthreads();
  }

  float mcol[4];
#pragma unroll
  for (int fn = 0; fn < 4; ++fn) mcol[fn] = meta[col0 + wn * 64 + fn * 16 + l16];
#pragma unroll
  for (int fm = 0; fm < 4; ++fm) {
#pragma unroll
    for (int fn = 0; fn < 4; ++fn) {
      int col = col0 + wn * 64 + fn * 16 + l16;
#pragma unroll
      for (int r = 0; r < 4; ++r) {
        size_t row = row0 + wm * 64 + fm * 16 + quad * 4 + r;
        out[row * H + col] = acc[fm][fn][r] * mcol[fn];
      }
    }
  }

  // --- vecmat appended to blocks 0..63 ---
  if (b < 64) {
    const int jx = b & 3, ky = b >> 2;
    if (tid < 64) {
      float s = 0.f;
      const float* p = &ws[WS_XSUMP + ky * 64 + tid];
#pragma unroll 8
      for (int q = 0; q < 256; ++q) s += p[q * H];
      xs[tid] = s;
      if (jx == 0) ws[WS_XSUM + ky * 64 + tid] = s;
    }
    __syncthreads();
    const int j = jx * 256 + tid;
    float s = 0.f;
#pragma unroll 8
    for (int k = 0; k < 64; ++k) s += xs[k] * W[(size_t)(ky * 64 + k) * H + j];
    ws[WS_ORAWP + ky * H + j] = s * (1.0f / (float)BATCH);
  }
}

// ---- K3: tail = finalize + new_w fused. 1024 blocks, one W-row each. ----
__global__ __launch_bounds__(256) void tail_kernel(const float* __restrict__ W,
                                                   const float* __restrict__ meta,
                                                   const float* __restrict__ act,
                                                   const int* __restrict__ ptr,
                                                   const float* __restrict__ targ,
                                                   const float* __restrict__ homeo,
                                                   const float* __restrict__ mlr,
                                                   const float* __restrict__ win,
                                                   const float* __restrict__ dec,
                                                   const float* __restrict__ ws,
                                                   float* __restrict__ out_w,
                                                   float* __restrict__ meta_out,
                                                   float* __restrict__ hist_out) {
  __shared__ float r1[4], r2[4];
  const int r = blockIdx.x;        // W row
  const int t = threadIdx.x;
  const int c4 = t * 4;

  // --- per-thread: reduce oraw partials for 4 columns, compute om ---
  f32x4 oraw = (f32x4){0.f, 0.f, 0.f, 0.f};
#pragma unroll
  for (int i = 0; i < 16; ++i) {
    const float4 v = *(const float4*)&ws[WS_ORAWP + i * H + c4];
    oraw[0] += v.x; oraw[1] += v.y; oraw[2] += v.z; oraw[3] += v.w;
  }
  const float4 mv = *(const float4*)&meta[c4];
  f32x4 om;
  om[0] = mv.x * oraw[0]; om[1] = mv.y * oraw[1];
  om[2] = mv.z * oraw[2]; om[3] = mv.w * oraw[3];

  // --- global sums: sum(om), sum(act) ---
  float s1 = om[0] + om[1] + om[2] + om[3];
  float s2 = 0.f;
#pragma unroll
  for (int j = 0; j < 4; ++j) {
    int idx = t + j * 256;
    if (idx < 1000) s2 += act[idx];
  }
#pragma unroll
  for (int o = 32; o > 0; o >>= 1) {
    s1 += __shfl_down(s1, o, 64);
    s2 += __shfl_down(s2, o, 64);
  }
  if ((t & 63) == 0) { r1[t >> 6] = s1; r2[t >> 6] = s2; }
  __syncthreads();
  const float ts1 = r1[0] + r1[1] + r1[2] + r1[3];
  const float ts2 = r2[0] + r2[1] + r2[2] + r2[3];
  const float total_mean = ts1 / (float)H;
  const int p = ptr[0];
  const float hist_mean = (ts2 - act[p] + total_mean) / 1000.f;
  const float scale = 1.f + homeo[0] * (targ[0] - hist_mean);
  const float w99 = 0.01f * expf(-win[0] * dec[0]);

  // --- row scalars (wave-uniform loads) ---
  float oraw_r = 0.f;
#pragma unroll
  for (int i = 0; i < 16; ++i) oraw_r += ws[WS_ORAWP + i * H + r];
  const float om_r = meta[r] * oraw_r;
  float negh_r = 0.f;
#pragma unroll
  for (int i = 0; i < 5; ++i) negh_r += ws[WS_NEGHP + i * H + r];
  const float neg_r = negh_r + w99 * om_r;

  // --- per-thread column vectors: posv, xsum ---
  f32x4 pv = (f32x4){0.f, 0.f, 0.f, 0.f};
#pragma unroll
  for (int i = 0; i < 5; ++i) {
    const float4 v = *(const float4*)&ws[WS_POSVP + i * H + c4];
    pv[0] += v.x; pv[1] += v.y; pv[2] += v.z; pv[3] += v.w;
  }
  const float4 xv = *(const float4*)&ws[WS_XSUM + c4];
  float xx[4] = {xv.x, xv.y, xv.z, xv.w};
  const float4 wv = *(const float4*)&W[(size_t)r * H + c4];
  float wx[4] = {wv.x, wv.y, wv.z, wv.w};
  float4 o;
  float ox[4];
#pragma unroll
  for (int i = 0; i < 4; ++i) {
    float v = wx[i] + om_r * pv[i] - neg_r * (xx[i] * (1.0f / (float)BATCH));
    v = fminf(fmaxf(v, -1.f), 1.f);
    v = v * scale;
    ox[i] = fminf(fmaxf(v, -1.f), 1.f);
  }
  o.x = ox[0]; o.y = ox[1]; o.z = ox[2]; o.w = ox[3];
  *(float4*)&out_w[(size_t)r * H + c4] = o;

  // --- block 0: meta_out + hist_out ---
  if (r == 0) {
    float4 nm;
    float nx[4] = {mv.x, mv.y, mv.z, mv.w};
    float nr[4];
#pragma unroll
    for (int i = 0; i < 4; ++i) {
      float v = nx[i] + mlr[0] * (om[i] - nx[i]);
      nr[i] = fminf(fmaxf(v, 0.f), 2.f);
    }
    nm.x = nr[0]; nm.y = nr[1]; nm.z = nr[2]; nm.w = nr[3];
    *(float4*)&meta_out[c4] = nm;
#pragma unroll
    for (int j = 0; j < 4; ++j) {
      int idx = t + j * 256;
      if (idx < 1000) hist_out[idx] = (idx == p) ? total_mean : act[idx];
    }
  }
}

// ================= LEGACY FALLBACK (small ws) =================
__global__ __launch_bounds__(256) void colsum_kernel(const float* __restrict__ x,
                                                     float* __restrict__ xsum) {
  int col = blockIdx.x * 256 + threadIdx.x;
  size_t r0 = (size_t)blockIdx.y * 256;
  float s = 0.f;
#pragma unroll 8
  for (int r = 0; r < 256; ++r) s += x[(r0 + r) * H + col];
  atomicAdd(&xsum[col], s);
}

__global__ __launch_bounds__(256) void gemm_fallback_kernel(const float* __restrict__ X,
                                                            const float* __restrict__ W,
                                                            const float* __restrict__ meta,
                                                            float* __restrict__ out) {
  __shared__ __align__(16) u16 lA[128][40];
  __shared__ __align__(16) u16 lB[128][40];
  const int tid = threadIdx.x;
  const int wave = tid >> 6;
  const int lane = tid & 63;
  const int quad = lane >> 4;
  const int l16 = lane & 15;
  const int wm = wave >> 1, wn = wave & 1;
  const size_t row0 = (size_t)blockIdx.x * 128;
  const int col0 = blockIdx.y * 128;
  f32x4 acc[4][4];
#pragma unroll
  for (int i = 0; i < 4; ++i)
#pragma unroll
    for (int j = 0; j < 4; ++j) acc[i][j] = (f32x4){0.f, 0.f, 0.f, 0.f};
  for (int k0 = 0; k0 < H; k0 += 32) {
#pragma unroll
    for (int i = 0; i < 4; ++i) {
      int idx = i * 256 + tid;
      int r = idx >> 3, c4 = idx & 7;
      const float4 v = *(const float4*)&X[(row0 + r) * H + k0 + c4 * 4];
      ushort4 h;
      h.x = f2bf(v.x); h.y = f2bf(v.y); h.z = f2bf(v.z); h.w = f2bf(v.w);
      *(ushort4*)&lA[r][c4 * 4] = h;
    }
#pragma unroll
    for (int i = 0; i < 4; ++i) {
      int idx = i * 256 + tid;
      int kk = idx >> 5, c4 = idx & 31;
      const float4 v = *(const float4*)&W[(size_t)(k0 + kk) * H + col0 + c4 * 4];
      lB[c4 * 4 + 0][kk] = f2bf(v.x);
      lB[c4 * 4 + 1][kk] = f2bf(v.y);
      lB[c4 * 4 + 2][kk] = f2bf(v.z);
      lB[c4 * 4 + 3][kk] = f2bf(v.w);
    }
    __syncthreads();
    bf16x8 av[4], bv[4];
#pragma unroll
    for (int f = 0; f < 4; ++f) {
      av[f] = __builtin_bit_cast(bf16x8, *(const u16x8*)&lA[wm * 64 + f * 16 + l16][quad * 8]);
      bv[f] = __builtin_bit_cast(bf16x8, *(const u16x8*)&lB[wn * 64 + f * 16 + l16][quad * 8]);
    }
#pragma unroll
    for (int fm = 0; fm < 4; ++fm)
#pragma unroll
      for (int fn = 0; fn < 4; ++fn)
        acc[fm][fn] = __builtin_amdgcn_mfma_f32_16x16x32_bf16(av[fm], bv[fn], acc[fm][fn], 0, 0, 0);
    __syncthreads();
  }
  float mcol[4];
#pragma unroll
  for (int fn = 0; fn < 4; ++fn) mcol[fn] = meta[col0 + wn * 64 + fn * 16 + l16];
#pragma unroll
  for (int fm = 0; fm < 4; ++fm) {
#pragma unroll
    for (int fn = 0; fn < 4; ++fn) {
      int col = col0 + wn * 64 + fn * 16 + l16;
#pragma unroll
      for (int r = 0; r < 4; ++r) {
        size_t row = row0 + wm * 64 + fm * 16 + quad * 4 + r;
        out[row * H + col] = acc[fm][fn][r] * mcol[fn];
      }
    }
  }
}

__global__ __launch_bounds__(256) void vecmat_kernel(const float* __restrict__ W,
                                                     const float* __restrict__ xsum,
                                                     float* __restrict__ outraw) {
  int j = blockIdx.x * 256 + threadIdx.x;
  int k0 = blockIdx.y * 64;
  float s = 0.f;
#pragma unroll 8
  for (int k = 0; k < 64; ++k) s += xsum[k0 + k] * W[(size_t)(k0 + k) * H + j];
  atomicAdd(&outraw[j], s * (1.0f / (float)BATCH));
}

__global__ __launch_bounds__(256) void stdpvec_kernel(const float* __restrict__ pre,
                                                      const float* __restrict__ post,
                                                      const float* __restrict__ win,
                                                      const float* __restrict__ dec,
                                                      float* __restrict__ posv,
                                                      float* __restrict__ negh) {
  int col = blockIdx.x * 256 + threadIdx.x;
  int t0 = 1 + blockIdx.y * 20;
  float wd = win[0] * dec[0];
  float ps = 0.f, ns = 0.f;
  int tend = t0 + 20;
  if (tend > 100) tend = 100;
  for (int t = t0; t < tend; ++t) {
    float w = 0.01f * expf(-(float)(101 - t) * wd);
    ps += w * pre[t * H + col];
    if (t >= 2) ns += w * post[t * H + col];
  }
  atomicAdd(&posv[col], ps);
  atomicAdd(&negh[col], ns);
}

__global__ __launch_bounds__(1024) void finalize_kernel(const float* __restrict__ meta,
                                                        const float* __restrict__ act,
                                                        const int* __restrict__ ptr,
                                                        const float* __restrict__ targ,
                                                        const float* __restrict__ homeo,
                                                        const float* __restrict__ mlr,
                                                        const float* __restrict__ outraw,
                                                        float* __restrict__ outmean,
                                                        float* __restrict__ scalep,
                                                        float* __restrict__ meta_out,
                                                        float* __restrict__ hist_out) {
  __shared__ float r1[16], r2[16];
  __shared__ float sc[2];
  int t = threadIdx.x;
  float om = meta[t] * outraw[t];
  outmean[t] = om;
  float a = (t < 1000) ? act[t] : 0.f;
  float s1 = om, s2 = a;
#pragma unroll
  for (int o = 32; o > 0; o >>= 1) {
    s1 += __shfl_down(s1, o, 64);
    s2 += __shfl_down(s2, o, 64);
  }
  if ((t & 63) == 0) { r1[t >> 6] = s1; r2[t >> 6] = s2; }
  __syncthreads();
  if (t == 0) {
    float ts1 = 0.f, ts2 = 0.f;
#pragma unroll
    for (int i = 0; i < 16; ++i) { ts1 += r1[i]; ts2 += r2[i]; }
    float total_mean = ts1 / (float)H;
    int p = ptr[0];
    float hist_mean = (ts2 - act[p] + total_mean) / 1000.f;
    float diff = targ[0] - hist_mean;
    sc[0] = 1.f + homeo[0] * diff;
    sc[1] = total_mean;
    scalep[0] = sc[0];
  }
  __syncthreads();
  float nm = meta[t] + mlr[0] * (om - meta[t]);
  nm = fminf(fmaxf(nm, 0.f), 2.f);
  meta_out[t] = nm;
  if (t < 1000) hist_out[t] = (t == ptr[0]) ? sc[1] : act[t];
}

__global__ __launch_bounds__(256) void neww_kernel(const float* __restrict__ W,
                                                   const float* __restrict__ outmean,
                                                   const float* __restrict__ posv,
                                                   const float* __restrict__ negh,
                                                   const float* __restrict__ xsum,
                                                   const float* __restrict__ scalep,
                                                   const float* __restrict__ win,
                                                   const float* __restrict__ dec,
                                                   float* __restrict__ out) {
  int idx4 = blockIdx.x * 256 + threadIdx.x;
  int rr = idx4 >> 8;
  int c4 = (idx4 & 255) * 4;
  float w99 = 0.01f * expf(-win[0] * dec[0]);
  float scale = scalep[0];
  float om_r = outmean[rr];
  float neg_r = negh[rr] + w99 * om_r;
  const float4 wv = *(const float4*)&W[(size_t)rr * H + c4];
  const float4 pv = *(const float4*)&posv[c4];
  const float4 xv = *(const float4*)&xsum[c4];
  float4 o;
  float vx[4] = {wv.x, wv.y, wv.z, wv.w};
  float px[4] = {pv.x, pv.y, pv.z, pv.w};
  float xx[4] = {xv.x, xv.y, xv.z, xv.w};
  float ox[4];
#pragma unroll
  for (int i = 0; i < 4; ++i) {
    float v = vx[i] + om_r * px[i] - neg_r * (xx[i] * (1.0f / (float)BATCH));
    v = fminf(fmaxf(v, -1.f), 1.f);
    v = v * scale;
    ox[i] = fminf(fmaxf(v, -1.f), 1.f);
  }
  o.x = ox[0]; o.y = ox[1]; o.z = ox[2]; o.w = ox[3];
  *(float4*)&out[(size_t)rr * H + c4] = o;
}

extern "C" void kernel_launch(void* const* d_in, const int* in_sizes, int n_in,
                              void* d_out, int out_size, void* d_ws, size_t ws_size,
                              hipStream_t stream) {
  const float* x     = (const float*)d_in[0];
  const float* W     = (const float*)d_in[1];
  const float* meta  = (const float*)d_in[2];
  const float* pre   = (const float*)d_in[3];
  const float* post  = (const float*)d_in[4];
  const float* act   = (const float*)d_in[5];
  const int*   ptr   = (const int*)d_in[6];
  const float* win   = (const float*)d_in[7];
  const float* dec   = (const float*)d_in[8];
  const float* targ  = (const float*)d_in[9];
  const float* homeo = (const float*)d_in[10];
  const float* mlr   = (const float*)d_in[11];

  float* out_y    = (float*)d_out;              // [B,H]
  float* out_w    = out_y + (size_t)BATCH * H;  // [H,H]
  float* out_meta = out_w + (size_t)H * H;      // [H]
  float* out_hist = out_meta + H;               // [1000]

  float* ws = (float*)d_ws;
  u16* Xb  = (u16*)(ws + WS_BF16);       // [B][H] bf16, 32 MB
  u16* Wbt = Xb + (size_t)BATCH * H;     // [H][H] bf16 transposed, 2 MB

  const size_t ws_need = (size_t)WS_BF16 * sizeof(float) +
                         ((size_t)BATCH * H + (size_t)H * H) * sizeof(u16);

  if (ws_size >= ws_need) {
    // fast path: 3 dispatches, no memset, no atomics
    prep_kernel<<<325, 1024, 0, stream>>>(x, W, Xb, Wbt, ws, pre, post, win, dec);
    gemm_vm_kernel<<<1024, 256, 0, stream>>>(Xb, Wbt, meta, W, ws, out_y);
    tail_kernel<<<1024, 256, 0, stream>>>(W, meta, act, ptr, targ, homeo, mlr,
                                          win, dec, ws, out_w, out_meta, out_hist);
  } else {
    // legacy path (atomics, in-gemm conversion)
    float* xsum    = ws;
    float* outraw  = ws + 1024;
    float* outmean = ws + 2048;
    float* posv    = ws + 3072;
    float* negh    = ws + 4096;
    float* scalep  = ws + 5120;
    hipMemsetAsync(d_ws, 0, 6144 * sizeof(float), stream);
    colsum_kernel<<<dim3(4, 64), 256, 0, stream>>>(x, xsum);
    gemm_fallback_kernel<<<dim3(128, 8), 256, 0, stream>>>(x, W, meta, out_y);
    vecmat_kernel<<<dim3(4, 16), 256, 0, stream>>>(W, xsum, outraw);
    stdpvec_kernel<<<dim3(4, 5), 256, 0, stream>>>(pre, post, win, dec, posv, negh);
    finalize_kernel<<<1, 1024, 0, stream>>>(meta, act, ptr, targ, homeo, mlr,
                                            outraw, outmean, scalep, out_meta, out_hist);
    neww_kernel<<<1024, 256, 0, stream>>>(W, outmean, posv, negh, xsum, scalep, win, dec, out_w);
  }
}